// Round 4
// baseline (2205.107 us; speedup 1.0000x reference)
//
#include <hip/hip_runtime.h>
#include <math.h>

#define BB 8
#define NN 4096
#define DD 1024
#define PP 16

static constexpr float DLOG2PI = 1881.9861160031696f; // 1024 * log(2*pi)
static constexpr float EPSC = 0.1f;

// W layout: Wmat[b][k][32] interleaved pairs: [j*2]=invS_j(k), [j*2+1]=mu_j(k)*invS_j(k)

// ---------------------------------------------------------------------------
// k_init: build Wmat + cns[b][j] = log pi - 0.5*(d log2pi + sum log S + sum mu^2/S)
// grid (16 j, 8 b), 256 threads (4 d each)
// ---------------------------------------------------------------------------
__global__ __launch_bounds__(256) void k_init(const float* __restrict__ m,
                                              const float* __restrict__ V_,
                                              float* __restrict__ Wmat,
                                              float* __restrict__ cns)
{
    int j = blockIdx.x, b = blockIdx.y;
    int tid = threadIdx.x;
    __shared__ float red[512];
    int d0 = tid * 4;
    float4 m4 = *(const float4*)(m + j * DD + d0);
    float4 v4 = *(const float4*)(V_ + j * DD + d0);
    float mv[4] = {m4.x, m4.y, m4.z, m4.w};
    float vv[4] = {v4.x, v4.y, v4.z, v4.w};
    float* Wb = Wmat + (size_t)b * (DD * 32);
    float llog = 0.f, lmq = 0.f;
#pragma unroll
    for (int c = 0; c < 4; c++) {
        float V = EPSC * log1pf(expf(vv[c]));
        float inv = 1.0f / V;
        int d = d0 + c;
        Wb[d * 32 + j * 2] = inv;
        Wb[d * 32 + j * 2 + 1] = mv[c] * inv;
        llog += logf(V);
        lmq += mv[c] * mv[c] * inv;
    }
    red[tid] = llog; red[256 + tid] = lmq;
    __syncthreads();
    for (int s = 128; s > 0; s >>= 1) {
        if (tid < s) { red[tid] += red[tid + s]; red[256 + tid] += red[256 + tid + s]; }
        __syncthreads();
    }
    if (tid == 0)
        cns[b * PP + j] = logf(1.0f / 16.0f) - 0.5f * (DLOG2PI + red[0] + red[256]);
}

// ---------------------------------------------------------------------------
// k_estep_part: 128 rows x 16 j x klen k partial of (-0.5*S1 + S2) -> epart
// grid (32 tiles, KS, 8 b), 256 threads. 16-k strips: LDS = Asub[128*17]
// (8.5 KB) + Wsub[16*36] (2.3 KB) ~= 11 KB -> 8 blocks/CU, 32 waves/CU
// (hardware wave cap; was 7 blocks / 28 waves at 32-k strips).
// __launch_bounds__(256,8) caps VGPR at 64 (hand count ~55, no spill).
// Inner loop = round-0 known-best form (row-major Asub, broadcast reads:
// pad 17 gives banks {0,4,..,28}+k across ty -> conflict-free).
// ---------------------------------------------------------------------------
__global__ __launch_bounds__(256, 8) void k_estep_part(const float* __restrict__ X,
                                                       const float* __restrict__ Wmat,
                                                       float* __restrict__ epart,
                                                       int klen)
{
    int tile = blockIdx.x, ks = blockIdx.y, b = blockIdx.z;
    int n0 = tile * 128, k0 = ks * klen;
    const float* Xb = X + ((size_t)b * NN + n0) * DD + k0;
    const float* Wb = Wmat + (size_t)b * (DD * 32) + (size_t)k0 * 32;
    __shared__ float Asub[128 * 17];   // 8.5 KB
    __shared__ float Wsub[16 * 36];    // 2.3 KB
    int tid = threadIdx.x;
    int tx = tid & 7, ty = tid >> 3;   // tx: j-pair 2tx,2tx+1 ; ty: row group
    // staging map: float4 f = tid + i*256 -> row f>>2 (0..127), kq (f&3)*4
    int srow = tid >> 2;               // 0..63 (+64 for second float4)
    int skq  = (tid & 3) << 2;
    float acc1[4][2] = {{0.f,0.f},{0.f,0.f},{0.f,0.f},{0.f,0.f}};
    float acc2[4][2] = {{0.f,0.f},{0.f,0.f},{0.f,0.f},{0.f,0.f}};
    for (int kk = 0; kk < klen; kk += 16) {
        __syncthreads();
        {
            float4 v0 = *(const float4*)(Xb + (size_t)srow * DD + kk + skq);
            float4 v1 = *(const float4*)(Xb + (size_t)(srow + 64) * DD + kk + skq);
            Asub[srow * 17 + skq + 0] = v0.x;
            Asub[srow * 17 + skq + 1] = v0.y;
            Asub[srow * 17 + skq + 2] = v0.z;
            Asub[srow * 17 + skq + 3] = v0.w;
            Asub[(srow + 64) * 17 + skq + 0] = v1.x;
            Asub[(srow + 64) * 17 + skq + 1] = v1.y;
            Asub[(srow + 64) * 17 + skq + 2] = v1.z;
            Asub[(srow + 64) * 17 + skq + 3] = v1.w;
        }
        if (tid < 128) {
            int k = tid >> 3, cq = (tid & 7) << 2;
            *(float4*)(Wsub + k * 36 + cq) = *(const float4*)(Wb + (size_t)(kk + k) * 32 + cq);
        }
        __syncthreads();
#pragma unroll
        for (int k = 0; k < 16; k++) {
            float4 w = *(const float4*)(Wsub + k * 36 + tx * 4);
            float a0 = Asub[(ty * 4 + 0) * 17 + k];
            float a1 = Asub[(ty * 4 + 1) * 17 + k];
            float a2 = Asub[(ty * 4 + 2) * 17 + k];
            float a3 = Asub[(ty * 4 + 3) * 17 + k];
            float s0 = a0 * a0, s1 = a1 * a1, s2 = a2 * a2, s3 = a3 * a3;
            acc1[0][0] += s0 * w.x; acc2[0][0] += a0 * w.y; acc1[0][1] += s0 * w.z; acc2[0][1] += a0 * w.w;
            acc1[1][0] += s1 * w.x; acc2[1][0] += a1 * w.y; acc1[1][1] += s1 * w.z; acc2[1][1] += a1 * w.w;
            acc1[2][0] += s2 * w.x; acc2[2][0] += a2 * w.y; acc1[2][1] += s2 * w.z; acc2[2][1] += a2 * w.w;
            acc1[3][0] += s3 * w.x; acc2[3][0] += a3 * w.y; acc1[3][1] += s3 * w.z; acc2[3][1] += a3 * w.w;
        }
    }
    float* ep = epart + (((size_t)ks * BB + b) * NN + n0) * PP;
#pragma unroll
    for (int r = 0; r < 4; r++) {
        float2 v = make_float2(-0.5f * acc1[r][0] + acc2[r][0],
                               -0.5f * acc1[r][1] + acc2[r][1]);
        *(float2*)(ep + (ty * 4 + r) * PP + tx * 2) = v;
    }
}

// ---------------------------------------------------------------------------
// k_ereduce: sum nparts k-partials + cns, softmax over 16 j, * mask -> qq,
// PLUS per-block wsum partials (64-lane shfl butterfly) -> wsump[chunk][b][16]
// grid (32 chunks of 128 rows, 8 b), 128 threads (1 row each)
// ---------------------------------------------------------------------------
__global__ __launch_bounds__(128) void k_ereduce(const float* __restrict__ epart,
                                                 const float* __restrict__ mask,
                                                 const float* __restrict__ cns,
                                                 float* __restrict__ qq,
                                                 float* __restrict__ wsump,
                                                 int nparts)
{
    int chunk = blockIdx.x, b = blockIdx.y;
    int tid = threadIdx.x;
    int n = chunk * 128 + tid;
    __shared__ float cs[16];
    __shared__ float wpart[2][16];
    if (tid < 16) cs[tid] = cns[b * PP + tid];
    __syncthreads();
    float jl[16];
#pragma unroll
    for (int q = 0; q < 4; q++) {
        float4 v = *(const float4*)(epart + ((size_t)b * NN + n) * PP + q * 4);
        jl[q * 4 + 0] = v.x; jl[q * 4 + 1] = v.y; jl[q * 4 + 2] = v.z; jl[q * 4 + 3] = v.w;
    }
    for (int ks = 1; ks < nparts; ks++) {
#pragma unroll
        for (int q = 0; q < 4; q++) {
            float4 v = *(const float4*)(epart + (((size_t)ks * BB + b) * NN + n) * PP + q * 4);
            jl[q * 4 + 0] += v.x; jl[q * 4 + 1] += v.y; jl[q * 4 + 2] += v.z; jl[q * 4 + 3] += v.w;
        }
    }
    float mx = -3.4e38f;
#pragma unroll
    for (int j = 0; j < 16; j++) { jl[j] += cs[j]; mx = fmaxf(mx, jl[j]); }
    float sum = 0.f;
#pragma unroll
    for (int j = 0; j < 16; j++) { jl[j] = expf(jl[j] - mx); sum += jl[j]; }
    float r = mask[(size_t)b * NN + n] / sum;
#pragma unroll
    for (int j = 0; j < 16; j++) jl[j] *= r;
    float* qo = qq + ((size_t)b * NN + n) * PP;
#pragma unroll
    for (int q = 0; q < 4; q++)
        *(float4*)(qo + q * 4) = make_float4(jl[q * 4 + 0], jl[q * 4 + 1],
                                             jl[q * 4 + 2], jl[q * 4 + 3]);
    // wave butterfly reduce of q over 64 lanes (row dim), then combine 2 waves
#pragma unroll
    for (int mz = 32; mz > 0; mz >>= 1) {
#pragma unroll
        for (int j = 0; j < 16; j++) jl[j] += __shfl_xor(jl[j], mz);
    }
    if ((tid & 63) == 0) {
#pragma unroll
        for (int j = 0; j < 16; j++) wpart[tid >> 6][j] = jl[j];
    }
    __syncthreads();
    if (tid < 16)
        wsump[((size_t)chunk * BB + b) * PP + tid] = wpart[0][tid] + wpart[1][tid];
}

// ---------------------------------------------------------------------------
// k_mstep: partial wxsum/wxxsum. grid (16 chunks of 64 cols, 8 nq of 512 rows, 8 b)
// thread: cg=4 cols, rg=rows n%8, jh=half of j (8 j's). acc 8x4 x2 = 64 VGPR:
// __launch_bounds__(256,4) -> 4 waves/SIMD, 16 waves/CU.
// ---------------------------------------------------------------------------
__global__ __launch_bounds__(256, 4) void k_mstep(const float* __restrict__ X,
                                                  const float* __restrict__ qq,
                                                  float* __restrict__ wxp,
                                                  float* __restrict__ wxxp)
{
    int cc = blockIdx.x, nq = blockIdx.y, b = blockIdx.z;
    int tid = threadIdx.x;
    int cg = tid & 15;           // 16 col groups of 4 cols
    int rg = (tid >> 4) & 7;     // 8 row groups
    int jh = tid >> 7;           // j half (j = jh*8 .. jh*8+7)
    int col0 = cc * 64 + cg * 4;
    const float* Xb = X + ((size_t)b * NN + nq * 512) * DD;
    const float* qb = qq + ((size_t)b * NN + nq * 512) * PP;
    float aw[8][4] = {};
    float ax[8][4] = {};
    for (int i = 0; i < 64; i++) {
        int n = i * 8 + rg;
        float4 x = *(const float4*)(Xb + (size_t)n * DD + col0);
        const float4 q0 = *(const float4*)(qb + n * PP + jh * 8);
        const float4 q1 = *(const float4*)(qb + n * PP + jh * 8 + 4);
        float x2x = x.x * x.x, x2y = x.y * x.y, x2z = x.z * x.z, x2w = x.w * x.w;
        float qv[8] = {q0.x, q0.y, q0.z, q0.w, q1.x, q1.y, q1.z, q1.w};
#pragma unroll
        for (int jj = 0; jj < 8; jj++) {
            float qj = qv[jj];
            aw[jj][0] += qj * x.x; aw[jj][1] += qj * x.y; aw[jj][2] += qj * x.z; aw[jj][3] += qj * x.w;
            ax[jj][0] += qj * x2x; ax[jj][1] += qj * x2y; ax[jj][2] += qj * x2z; ax[jj][3] += qj * x2w;
        }
    }
    // cross-rg reduction per j-half: red[rg][jj][68] (+4 pad/row, stride 548)
    __shared__ float red[8 * 548]; // 17.5 KB
#pragma unroll
    for (int ph = 0; ph < 4; ph++) {
        int jb = (ph & 1) * 8;
        __syncthreads();
        if (jh == (ph & 1)) {
#pragma unroll
            for (int jj = 0; jj < 8; jj++) {
                float4 v;
                if (ph < 2) v = make_float4(aw[jj][0], aw[jj][1], aw[jj][2], aw[jj][3]);
                else        v = make_float4(ax[jj][0], ax[jj][1], ax[jj][2], ax[jj][3]);
                *(float4*)(red + rg * 548 + jj * 68 + cg * 4) = v;
            }
        }
        __syncthreads();
        float* dst = (ph < 2) ? wxp : wxxp;
#pragma unroll
        for (int o = 0; o < 2; o++) {
            int idx = tid + o * 256;
            int jj = idx >> 6, c = idx & 63;
            float s = 0.f;
#pragma unroll
            for (int g = 0; g < 8; g++) s += red[g * 548 + jj * 68 + c];
            dst[(((size_t)b * 8 + nq) * PP + jb + jj) * DD + cc * 64 + c] = s;
        }
    }
}

// ---------------------------------------------------------------------------
// k_finalize: reduce partials -> pi, mu, Sigma (d_out) and next-iter W, cns.
// grid (16 j, 8 b), 256 threads (4 d each). wsum now read from wsump
// (32 chunk-partials) instead of re-reading 256 KB of qq per block.
// ---------------------------------------------------------------------------
__global__ __launch_bounds__(256) void k_finalize(const float* __restrict__ wsump,
                                                  const float* __restrict__ wxp,
                                                  const float* __restrict__ wxxp,
                                                  const float* __restrict__ m,
                                                  const float* __restrict__ V_,
                                                  float* __restrict__ pi,
                                                  float* __restrict__ mu,
                                                  float* __restrict__ Sigma,
                                                  float* __restrict__ Wmat,
                                                  float* __restrict__ cns)
{
    int j = blockIdx.x, b = blockIdx.y;
    int tid = threadIdx.x;
    __shared__ float red[512];
    __shared__ float wsr[16];
    __shared__ float sden;
    if (tid < 16) {
        float s = 0.f;
#pragma unroll
        for (int c = 0; c < 32; c++) s += wsump[((size_t)c * BB + b) * PP + tid];
        wsr[tid] = s + 1.0f; // + TAU
    }
    __syncthreads();
    if (tid == 0) {
        float dd = 0.f;
#pragma unroll
        for (int jj = 0; jj < 16; jj++) dd += wsr[jj];
        sden = dd;
    }
    __syncthreads();
    float rws = 1.0f / wsr[j];
    float pij = wsr[j] / sden;
    int d0 = tid * 4;
    float wxa[4] = {0, 0, 0, 0}, wxxa[4] = {0, 0, 0, 0};
#pragma unroll
    for (int g = 0; g < 8; g++) {
        const float4 a = *(const float4*)(wxp + (((size_t)b * 8 + g) * PP + j) * DD + d0);
        wxa[0] += a.x; wxa[1] += a.y; wxa[2] += a.z; wxa[3] += a.w;
        const float4 c2 = *(const float4*)(wxxp + (((size_t)b * 8 + g) * PP + j) * DD + d0);
        wxxa[0] += c2.x; wxxa[1] += c2.y; wxxa[2] += c2.z; wxxa[3] += c2.w;
    }
    float4 m4 = *(const float4*)(m + j * DD + d0);
    float4 v4 = *(const float4*)(V_ + j * DD + d0);
    float mvv[4] = {m4.x, m4.y, m4.z, m4.w};
    float vvv[4] = {v4.x, v4.y, v4.z, v4.w};
    float muo[4], sgo[4];
    float llog = 0.f, lmq = 0.f;
    float* Wb = Wmat + (size_t)b * (DD * 32);
#pragma unroll
    for (int c = 0; c < 4; c++) {
        float V = EPSC * log1pf(expf(vvv[c]));
        float muv = (wxa[c] + mvv[c]) * rws;                       // tau = 1
        float Sg = (wxxa[c] + V + mvv[c] * mvv[c]) * rws - muv * muv;
        float inv = 1.0f / Sg;
        muo[c] = muv; sgo[c] = Sg;
        int d = d0 + c;
        Wb[d * 32 + j * 2] = inv;
        Wb[d * 32 + j * 2 + 1] = muv * inv;
        llog += logf(Sg);
        lmq += muv * muv * inv;
    }
    *(float4*)(mu + ((size_t)b * PP + j) * DD + d0) = make_float4(muo[0], muo[1], muo[2], muo[3]);
    *(float4*)(Sigma + ((size_t)b * PP + j) * DD + d0) = make_float4(sgo[0], sgo[1], sgo[2], sgo[3]);
    red[tid] = llog; red[256 + tid] = lmq;
    __syncthreads();
    for (int s = 128; s > 0; s >>= 1) {
        if (tid < s) { red[tid] += red[tid + s]; red[256 + tid] += red[256 + tid + s]; }
        __syncthreads();
    }
    if (tid == 0) {
        pi[b * PP + j] = pij;
        cns[b * PP + j] = logf(pij) - 0.5f * (DLOG2PI + red[0] + red[256]);
    }
}

extern "C" void kernel_launch(void* const* d_in, const int* in_sizes, int n_in,
                              void* d_out, int out_size, void* d_ws, size_t ws_size,
                              hipStream_t stream)
{
    (void)in_sizes; (void)n_in; (void)out_size;
    const float* data = (const float*)d_in[0];
    const float* mask = (const float*)d_in[1];
    const float* m    = (const float*)d_in[2];
    const float* V_   = (const float*)d_in[3];

    float* out = (float*)d_out;
    float* pi  = out;                       // 128
    float* mu  = out + 128;                 // 131072
    float* Sg  = out + 128 + 131072;        // 131072
    float* qq  = out + 128 + 2 * 131072;    // 524288

    // k-split for e-step: prefer 8 (occupancy) if workspace allows, else 4.
    size_t need8 = ((size_t)262272 + (size_t)8 * BB * NN * PP
                    + (size_t)2 * BB * 8 * PP * DD + 32 * BB * PP) * sizeof(float);
    int KS = (ws_size >= need8) ? 8 : 4;
    int klen = DD / KS;

    float* ws    = (float*)d_ws;
    float* Wmat  = ws;                        // 8*1024*32 = 262144
    float* cns   = ws + 262144;               // 128
    float* epart = ws + 262272;               // KS*8*4096*16
    float* wxp   = epart + (size_t)KS * BB * NN * PP;
    float* wxxp  = wxp + (size_t)BB * 8 * PP * DD;
    float* wsump = wxxp + (size_t)BB * 8 * PP * DD;   // 32*8*16 = 4096

    k_init<<<dim3(16, 8), 256, 0, stream>>>(m, V_, Wmat, cns);
    for (int it = 0; it < 3; it++) {
        k_estep_part<<<dim3(32, KS, 8), 256, 0, stream>>>(data, Wmat, epart, klen);
        k_ereduce<<<dim3(32, 8), 128, 0, stream>>>(epart, mask, cns, qq, wsump, KS);
        k_mstep<<<dim3(16, 8, 8), 256, 0, stream>>>(data, qq, wxp, wxxp);
        k_finalize<<<dim3(16, 8), 256, 0, stream>>>(wsump, wxp, wxxp, m, V_, pi, mu, Sg, Wmat, cns);
    }
}

// Round 5
// 432.289 us; speedup vs baseline: 5.1010x; 5.1010x over previous
//
#include <hip/hip_runtime.h>
#include <math.h>

#define BB 8
#define NN 4096
#define DD 1024
#define PP 16

static constexpr float DLOG2PI = 1881.9861160031696f; // 1024 * log(2*pi)
static constexpr float EPSC = 0.1f;

// W layout: Wmat[b][k][32] interleaved pairs: [j*2]=invS_j(k), [j*2+1]=mu_j(k)*invS_j(k)

// ---------------------------------------------------------------------------
// k_init: build Wmat + cns[b][j] = log pi - 0.5*(d log2pi + sum log S + sum mu^2/S)
// grid (16 j, 8 b), 256 threads (4 d each)
// ---------------------------------------------------------------------------
__global__ __launch_bounds__(256) void k_init(const float* __restrict__ m,
                                              const float* __restrict__ V_,
                                              float* __restrict__ Wmat,
                                              float* __restrict__ cns)
{
    int j = blockIdx.x, b = blockIdx.y;
    int tid = threadIdx.x;
    __shared__ float red[512];
    int d0 = tid * 4;
    float4 m4 = *(const float4*)(m + j * DD + d0);
    float4 v4 = *(const float4*)(V_ + j * DD + d0);
    float mv[4] = {m4.x, m4.y, m4.z, m4.w};
    float vv[4] = {v4.x, v4.y, v4.z, v4.w};
    float* Wb = Wmat + (size_t)b * (DD * 32);
    float llog = 0.f, lmq = 0.f;
#pragma unroll
    for (int c = 0; c < 4; c++) {
        float V = EPSC * log1pf(expf(vv[c]));
        float inv = 1.0f / V;
        int d = d0 + c;
        Wb[d * 32 + j * 2] = inv;
        Wb[d * 32 + j * 2 + 1] = mv[c] * inv;
        llog += logf(V);
        lmq += mv[c] * mv[c] * inv;
    }
    red[tid] = llog; red[256 + tid] = lmq;
    __syncthreads();
    for (int s = 128; s > 0; s >>= 1) {
        if (tid < s) { red[tid] += red[tid + s]; red[256 + tid] += red[256 + tid + s]; }
        __syncthreads();
    }
    if (tid == 0)
        cns[b * PP + j] = logf(1.0f / 16.0f) - 0.5f * (DLOG2PI + red[0] + red[256]);
}

// ---------------------------------------------------------------------------
// k_estep_part: 128 rows x 16 j x klen k partial of (-0.5*S1 + S2) -> epart
// grid (32 tiles, KS, 8 b), 256 threads. KS=8, 32-k strips (128 B per row
// per strip = FULL cache line; 16-k strips caused 6.7x HBM overfetch, R4).
// LDS = Asub[128*33] 16.9 KB + Wsub[32*36] 4.6 KB -> 7 blocks/CU, 28 waves.
// Round-3 verified-best form; DO NOT shrink the per-row strip below 128 B.
// ---------------------------------------------------------------------------
__global__ __launch_bounds__(256) void k_estep_part(const float* __restrict__ X,
                                                    const float* __restrict__ Wmat,
                                                    float* __restrict__ epart,
                                                    int klen)
{
    int tile = blockIdx.x, ks = blockIdx.y, b = blockIdx.z;
    int n0 = tile * 128, k0 = ks * klen;
    const float* Xb = X + ((size_t)b * NN + n0) * DD + k0;
    const float* Wb = Wmat + (size_t)b * (DD * 32) + (size_t)k0 * 32;
    __shared__ float Asub[128 * 33];   // 16.9 KB
    __shared__ float Wsub[32 * 36];    // 4.6 KB
    int tid = threadIdx.x;
    int tx = tid & 7, ty = tid >> 3;   // tx: j-pair 2tx,2tx+1 ; ty: row group
    float acc1[4][2] = {{0.f,0.f},{0.f,0.f},{0.f,0.f},{0.f,0.f}};
    float acc2[4][2] = {{0.f,0.f},{0.f,0.f},{0.f,0.f},{0.f,0.f}};
    for (int kk = 0; kk < klen; kk += 32) {
        __syncthreads();
#pragma unroll
        for (int i = 0; i < 4; i++) {
            int f = tid + i * 256;
            int row = f >> 3;
            int kq = (f & 7) << 2;
            float4 v = *(const float4*)(Xb + (size_t)row * DD + kk + kq);
            Asub[row * 33 + kq + 0] = v.x;
            Asub[row * 33 + kq + 1] = v.y;
            Asub[row * 33 + kq + 2] = v.z;
            Asub[row * 33 + kq + 3] = v.w;
        }
        {
            int k = tid >> 3, cq = (tid & 7) << 2;
            *(float4*)(Wsub + k * 36 + cq) = *(const float4*)(Wb + (size_t)(kk + k) * 32 + cq);
        }
        __syncthreads();
#pragma unroll 8
        for (int k = 0; k < 32; k++) {
            float4 w = *(const float4*)(Wsub + k * 36 + tx * 4);
            float a0 = Asub[(ty * 4 + 0) * 33 + k];
            float a1 = Asub[(ty * 4 + 1) * 33 + k];
            float a2 = Asub[(ty * 4 + 2) * 33 + k];
            float a3 = Asub[(ty * 4 + 3) * 33 + k];
            float s0 = a0 * a0, s1 = a1 * a1, s2 = a2 * a2, s3 = a3 * a3;
            acc1[0][0] += s0 * w.x; acc2[0][0] += a0 * w.y; acc1[0][1] += s0 * w.z; acc2[0][1] += a0 * w.w;
            acc1[1][0] += s1 * w.x; acc2[1][0] += a1 * w.y; acc1[1][1] += s1 * w.z; acc2[1][1] += a1 * w.w;
            acc1[2][0] += s2 * w.x; acc2[2][0] += a2 * w.y; acc1[2][1] += s2 * w.z; acc2[2][1] += a2 * w.w;
            acc1[3][0] += s3 * w.x; acc2[3][0] += a3 * w.y; acc1[3][1] += s3 * w.z; acc2[3][1] += a3 * w.w;
        }
    }
    float* ep = epart + (((size_t)ks * BB + b) * NN + n0) * PP;
#pragma unroll
    for (int r = 0; r < 4; r++) {
        float2 v = make_float2(-0.5f * acc1[r][0] + acc2[r][0],
                               -0.5f * acc1[r][1] + acc2[r][1]);
        *(float2*)(ep + (ty * 4 + r) * PP + tx * 2) = v;
    }
}

// ---------------------------------------------------------------------------
// k_ereduce: sum nparts k-partials + cns, softmax over 16 j, * mask -> qq,
// PLUS per-block wsum partials (64-lane shfl butterfly) -> wsump[chunk][b][16]
// grid (32 chunks of 128 rows, 8 b), 128 threads (1 row each)
// ---------------------------------------------------------------------------
__global__ __launch_bounds__(128) void k_ereduce(const float* __restrict__ epart,
                                                 const float* __restrict__ mask,
                                                 const float* __restrict__ cns,
                                                 float* __restrict__ qq,
                                                 float* __restrict__ wsump,
                                                 int nparts)
{
    int chunk = blockIdx.x, b = blockIdx.y;
    int tid = threadIdx.x;
    int n = chunk * 128 + tid;
    __shared__ float cs[16];
    __shared__ float wpart[2][16];
    if (tid < 16) cs[tid] = cns[b * PP + tid];
    __syncthreads();
    float jl[16];
#pragma unroll
    for (int q = 0; q < 4; q++) {
        float4 v = *(const float4*)(epart + ((size_t)b * NN + n) * PP + q * 4);
        jl[q * 4 + 0] = v.x; jl[q * 4 + 1] = v.y; jl[q * 4 + 2] = v.z; jl[q * 4 + 3] = v.w;
    }
    for (int ks = 1; ks < nparts; ks++) {
#pragma unroll
        for (int q = 0; q < 4; q++) {
            float4 v = *(const float4*)(epart + (((size_t)ks * BB + b) * NN + n) * PP + q * 4);
            jl[q * 4 + 0] += v.x; jl[q * 4 + 1] += v.y; jl[q * 4 + 2] += v.z; jl[q * 4 + 3] += v.w;
        }
    }
    float mx = -3.4e38f;
#pragma unroll
    for (int j = 0; j < 16; j++) { jl[j] += cs[j]; mx = fmaxf(mx, jl[j]); }
    float sum = 0.f;
#pragma unroll
    for (int j = 0; j < 16; j++) { jl[j] = expf(jl[j] - mx); sum += jl[j]; }
    float r = mask[(size_t)b * NN + n] / sum;
#pragma unroll
    for (int j = 0; j < 16; j++) jl[j] *= r;
    float* qo = qq + ((size_t)b * NN + n) * PP;
#pragma unroll
    for (int q = 0; q < 4; q++)
        *(float4*)(qo + q * 4) = make_float4(jl[q * 4 + 0], jl[q * 4 + 1],
                                             jl[q * 4 + 2], jl[q * 4 + 3]);
    // wave butterfly reduce over 64 lanes (row dim), then combine 2 waves
#pragma unroll
    for (int mz = 32; mz > 0; mz >>= 1) {
#pragma unroll
        for (int j = 0; j < 16; j++) jl[j] += __shfl_xor(jl[j], mz);
    }
    if ((tid & 63) == 0) {
#pragma unroll
        for (int j = 0; j < 16; j++) wpart[tid >> 6][j] = jl[j];
    }
    __syncthreads();
    if (tid < 16)
        wsump[((size_t)chunk * BB + b) * PP + tid] = wpart[0][tid] + wpart[1][tid];
}

// ---------------------------------------------------------------------------
// k_mstep: partial wxsum/wxxsum. grid (16 chunks of 64 cols, 8 nq of 512 rows, 8 b)
// thread: cg=4 cols, rg=rows n%8, jh=half of j (8 j's). acc 8x4 x2 = 64 VGPR:
// __launch_bounds__(256,4) -> 4 waves/SIMD, 16 waves/CU.
// ---------------------------------------------------------------------------
__global__ __launch_bounds__(256, 4) void k_mstep(const float* __restrict__ X,
                                                  const float* __restrict__ qq,
                                                  float* __restrict__ wxp,
                                                  float* __restrict__ wxxp)
{
    int cc = blockIdx.x, nq = blockIdx.y, b = blockIdx.z;
    int tid = threadIdx.x;
    int cg = tid & 15;           // 16 col groups of 4 cols
    int rg = (tid >> 4) & 7;     // 8 row groups
    int jh = tid >> 7;           // j half (j = jh*8 .. jh*8+7)
    int col0 = cc * 64 + cg * 4;
    const float* Xb = X + ((size_t)b * NN + nq * 512) * DD;
    const float* qb = qq + ((size_t)b * NN + nq * 512) * PP;
    float aw[8][4] = {};
    float ax[8][4] = {};
    for (int i = 0; i < 64; i++) {
        int n = i * 8 + rg;
        float4 x = *(const float4*)(Xb + (size_t)n * DD + col0);
        const float4 q0 = *(const float4*)(qb + n * PP + jh * 8);
        const float4 q1 = *(const float4*)(qb + n * PP + jh * 8 + 4);
        float x2x = x.x * x.x, x2y = x.y * x.y, x2z = x.z * x.z, x2w = x.w * x.w;
        float qv[8] = {q0.x, q0.y, q0.z, q0.w, q1.x, q1.y, q1.z, q1.w};
#pragma unroll
        for (int jj = 0; jj < 8; jj++) {
            float qj = qv[jj];
            aw[jj][0] += qj * x.x; aw[jj][1] += qj * x.y; aw[jj][2] += qj * x.z; aw[jj][3] += qj * x.w;
            ax[jj][0] += qj * x2x; ax[jj][1] += qj * x2y; ax[jj][2] += qj * x2z; ax[jj][3] += qj * x2w;
        }
    }
    // cross-rg reduction per j-half: red[rg][jj][68] (+4 pad/row, stride 548)
    __shared__ float red[8 * 548]; // 17.5 KB
#pragma unroll
    for (int ph = 0; ph < 4; ph++) {
        int jb = (ph & 1) * 8;
        __syncthreads();
        if (jh == (ph & 1)) {
#pragma unroll
            for (int jj = 0; jj < 8; jj++) {
                float4 v;
                if (ph < 2) v = make_float4(aw[jj][0], aw[jj][1], aw[jj][2], aw[jj][3]);
                else        v = make_float4(ax[jj][0], ax[jj][1], ax[jj][2], ax[jj][3]);
                *(float4*)(red + rg * 548 + jj * 68 + cg * 4) = v;
            }
        }
        __syncthreads();
        float* dst = (ph < 2) ? wxp : wxxp;
#pragma unroll
        for (int o = 0; o < 2; o++) {
            int idx = tid + o * 256;
            int jj = idx >> 6, c = idx & 63;
            float s = 0.f;
#pragma unroll
            for (int g = 0; g < 8; g++) s += red[g * 548 + jj * 68 + c];
            dst[(((size_t)b * 8 + nq) * PP + jb + jj) * DD + cc * 64 + c] = s;
        }
    }
}

// ---------------------------------------------------------------------------
// k_finalize: reduce partials -> pi, mu, Sigma (d_out) and next-iter W, cns.
// grid (16 j, 8 b), 256 threads (4 d each). wsum read from wsump
// (32 chunk-partials) instead of re-reading 256 KB of qq per block.
// ---------------------------------------------------------------------------
__global__ __launch_bounds__(256) void k_finalize(const float* __restrict__ wsump,
                                                  const float* __restrict__ wxp,
                                                  const float* __restrict__ wxxp,
                                                  const float* __restrict__ m,
                                                  const float* __restrict__ V_,
                                                  float* __restrict__ pi,
                                                  float* __restrict__ mu,
                                                  float* __restrict__ Sigma,
                                                  float* __restrict__ Wmat,
                                                  float* __restrict__ cns)
{
    int j = blockIdx.x, b = blockIdx.y;
    int tid = threadIdx.x;
    __shared__ float red[512];
    __shared__ float wsr[16];
    __shared__ float sden;
    if (tid < 16) {
        float s = 0.f;
#pragma unroll
        for (int c = 0; c < 32; c++) s += wsump[((size_t)c * BB + b) * PP + tid];
        wsr[tid] = s + 1.0f; // + TAU
    }
    __syncthreads();
    if (tid == 0) {
        float dd = 0.f;
#pragma unroll
        for (int jj = 0; jj < 16; jj++) dd += wsr[jj];
        sden = dd;
    }
    __syncthreads();
    float rws = 1.0f / wsr[j];
    float pij = wsr[j] / sden;
    int d0 = tid * 4;
    float wxa[4] = {0, 0, 0, 0}, wxxa[4] = {0, 0, 0, 0};
#pragma unroll
    for (int g = 0; g < 8; g++) {
        const float4 a = *(const float4*)(wxp + (((size_t)b * 8 + g) * PP + j) * DD + d0);
        wxa[0] += a.x; wxa[1] += a.y; wxa[2] += a.z; wxa[3] += a.w;
        const float4 c2 = *(const float4*)(wxxp + (((size_t)b * 8 + g) * PP + j) * DD + d0);
        wxxa[0] += c2.x; wxxa[1] += c2.y; wxxa[2] += c2.z; wxxa[3] += c2.w;
    }
    float4 m4 = *(const float4*)(m + j * DD + d0);
    float4 v4 = *(const float4*)(V_ + j * DD + d0);
    float mvv[4] = {m4.x, m4.y, m4.z, m4.w};
    float vvv[4] = {v4.x, v4.y, v4.z, v4.w};
    float muo[4], sgo[4];
    float llog = 0.f, lmq = 0.f;
    float* Wb = Wmat + (size_t)b * (DD * 32);
#pragma unroll
    for (int c = 0; c < 4; c++) {
        float V = EPSC * log1pf(expf(vvv[c]));
        float muv = (wxa[c] + mvv[c]) * rws;                       // tau = 1
        float Sg = (wxxa[c] + V + mvv[c] * mvv[c]) * rws - muv * muv;
        float inv = 1.0f / Sg;
        muo[c] = muv; sgo[c] = Sg;
        int d = d0 + c;
        Wb[d * 32 + j * 2] = inv;
        Wb[d * 32 + j * 2 + 1] = muv * inv;
        llog += logf(Sg);
        lmq += muv * muv * inv;
    }
    *(float4*)(mu + ((size_t)b * PP + j) * DD + d0) = make_float4(muo[0], muo[1], muo[2], muo[3]);
    *(float4*)(Sigma + ((size_t)b * PP + j) * DD + d0) = make_float4(sgo[0], sgo[1], sgo[2], sgo[3]);
    red[tid] = llog; red[256 + tid] = lmq;
    __syncthreads();
    for (int s = 128; s > 0; s >>= 1) {
        if (tid < s) { red[tid] += red[tid + s]; red[256 + tid] += red[256 + tid + s]; }
        __syncthreads();
    }
    if (tid == 0) {
        pi[b * PP + j] = pij;
        cns[b * PP + j] = logf(pij) - 0.5f * (DLOG2PI + red[0] + red[256]);
    }
}

extern "C" void kernel_launch(void* const* d_in, const int* in_sizes, int n_in,
                              void* d_out, int out_size, void* d_ws, size_t ws_size,
                              hipStream_t stream)
{
    (void)in_sizes; (void)n_in; (void)out_size;
    const float* data = (const float*)d_in[0];
    const float* mask = (const float*)d_in[1];
    const float* m    = (const float*)d_in[2];
    const float* V_   = (const float*)d_in[3];

    float* out = (float*)d_out;
    float* pi  = out;                       // 128
    float* mu  = out + 128;                 // 131072
    float* Sg  = out + 128 + 131072;        // 131072
    float* qq  = out + 128 + 2 * 131072;    // 524288

    // k-split for e-step: prefer 8 (occupancy) if workspace allows, else 4.
    size_t need8 = ((size_t)262272 + (size_t)8 * BB * NN * PP
                    + (size_t)2 * BB * 8 * PP * DD + 32 * BB * PP) * sizeof(float);
    int KS = (ws_size >= need8) ? 8 : 4;
    int klen = DD / KS;

    float* ws    = (float*)d_ws;
    float* Wmat  = ws;                        // 8*1024*32 = 262144
    float* cns   = ws + 262144;               // 128
    float* epart = ws + 262272;               // KS*8*4096*16
    float* wxp   = epart + (size_t)KS * BB * NN * PP;
    float* wxxp  = wxp + (size_t)BB * 8 * PP * DD;
    float* wsump = wxxp + (size_t)BB * 8 * PP * DD;   // 32*8*16 = 4096

    k_init<<<dim3(16, 8), 256, 0, stream>>>(m, V_, Wmat, cns);
    for (int it = 0; it < 3; it++) {
        k_estep_part<<<dim3(32, KS, 8), 256, 0, stream>>>(data, Wmat, epart, klen);
        k_ereduce<<<dim3(32, 8), 128, 0, stream>>>(epart, mask, cns, qq, wsump, KS);
        k_mstep<<<dim3(16, 8, 8), 256, 0, stream>>>(data, qq, wxp, wxxp);
        k_finalize<<<dim3(16, 8), 256, 0, stream>>>(wsump, wxp, wxxp, m, V_, pi, mu, Sg, Wmat, cns);
    }
}